// Round 9
// baseline (263.650 us; speedup 1.0000x reference)
//
#include <hip/hip_runtime.h>
#include <hip/hip_bf16.h>
#include <math.h>

#define Bn 4
#define Sn 1024
#define Dn 2048
#define Hn 16
#define DHn 128
#define BS (Bn * Sn)       // 4096
#define QKVC (3 * Dn)      // 6144

typedef __attribute__((ext_vector_type(8))) short short8;   // 8 x bf16
typedef __attribute__((ext_vector_type(4))) float float4v;  // MFMA acc

// f32 -> bf16 (round-to-nearest-even)
__device__ inline unsigned short f2bf(float x) {
  union { float f; unsigned int u; } v; v.f = x;
  unsigned int r = v.u + 0x7fffu + ((v.u >> 16) & 1u);
  return (unsigned short)(r >> 16);
}
__device__ inline float bf2f(unsigned short b) {
  union { unsigned int u; float f; } v; v.u = ((unsigned int)b) << 16;
  return v.f;
}

// async global->LDS, 16B per lane. LDS dest = wave-uniform base + lane*16.
__device__ __forceinline__ void gload16(const unsigned short* g, unsigned short* l) {
  __builtin_amdgcn_global_load_lds(
      (const __attribute__((address_space(1))) unsigned int*)g,
      (__attribute__((address_space(3))) unsigned int*)l, 16, 0, 0);
}

// ---------------------------------------------------------------------------
// x f32 -> bf16, 8 elems/thread
// ---------------------------------------------------------------------------
__global__ __launch_bounds__(256) void cvt_f32_bf16(
    const float* __restrict__ in, unsigned short* __restrict__ out, int n8) {
  int id = blockIdx.x * 256 + threadIdx.x;
  if (id >= n8) return;
  const float4* p = reinterpret_cast<const float4*>(in) + 2 * (size_t)id;
  float4 a = p[0], b = p[1];
  short8 o;
  o[0] = (short)f2bf(a.x); o[1] = (short)f2bf(a.y);
  o[2] = (short)f2bf(a.z); o[3] = (short)f2bf(a.w);
  o[4] = (short)f2bf(b.x); o[5] = (short)f2bf(b.y);
  o[6] = (short)f2bf(b.z); o[7] = (short)f2bf(b.w);
  *reinterpret_cast<short8*>(out + 8 * (size_t)id) = o;
}

// ---------------------------------------------------------------------------
// Weight transpose+convert: w [K][N] f32 -> wT [N][K] bf16. 64x64 tiles.
// ---------------------------------------------------------------------------
__global__ __launch_bounds__(256) void transpose_cvt(
    const float* __restrict__ w, unsigned short* __restrict__ wT, int K, int N) {
  __shared__ unsigned short t[64][72];
  const int c0 = blockIdx.x * 64;  // N
  const int r0 = blockIdx.y * 64;  // K
  const int tid = threadIdx.x;
  const int r = tid >> 2;
  const int cb = (tid & 3) * 16;
#pragma unroll
  for (int it = 0; it < 4; ++it) {
    float4 v = *reinterpret_cast<const float4*>(&w[(long)(r0 + r) * N + c0 + cb + 4 * it]);
    t[r][cb + 4 * it + 0] = f2bf(v.x);
    t[r][cb + 4 * it + 1] = f2bf(v.y);
    t[r][cb + 4 * it + 2] = f2bf(v.z);
    t[r][cb + 4 * it + 3] = f2bf(v.w);
  }
  __syncthreads();
  unsigned short o[16];
#pragma unroll
  for (int e = 0; e < 16; ++e) o[e] = t[cb + e][r];
  unsigned short* dst = &wT[(long)(c0 + r) * K + r0 + cb];
  *reinterpret_cast<short8*>(dst) = *reinterpret_cast<short8*>(&o[0]);
  *reinterpret_cast<short8*>(dst + 8) = *reinterpret_cast<short8*>(&o[8]);
}

// ---------------------------------------------------------------------------
// Shared 256x128-tile pipelined main loop (unchanged from R8).
// ---------------------------------------------------------------------------
#define AB8(buf, h) ((buf) * 16384 + (h) * 8192)      // shorts
#define BB8(buf) (32768 + (buf) * 8192)               // shorts

#define VMW(n)                                                                 \
  asm volatile("s_waitcnt vmcnt(" #n ")" ::: "memory");                        \
  __builtin_amdgcn_sched_barrier(0);

#define PHASE(BUF, MIH, STAGE_STMT, WAIT_STMT)                                 \
  {                                                                            \
    __builtin_amdgcn_sched_barrier(0);                                         \
    short8 afr[2][2];                                                          \
    _Pragma("unroll") for (int mi2 = 0; mi2 < 2; ++mi2) {                      \
      const int mrow = wr * 64 + ((MIH) * 2 + mi2) * 16;                       \
      const int hh = mrow >> 7;                                                \
      const int rl = (mrow & 127) + c;                                         \
      _Pragma("unroll") for (int ks = 0; ks < 2; ++ks)                         \
        afr[mi2][ks] = *(const short8*)(lds + AB8(BUF, 0) + hh * 8192 +        \
            rl * 64 + (((ks * 4 + g) ^ cg7) << 3));                            \
    }                                                                          \
    if ((MIH) == 0) {                                                          \
      _Pragma("unroll") for (int ni = 0; ni < 4; ++ni)                         \
        _Pragma("unroll") for (int ks = 0; ks < 2; ++ks)                       \
          bfr[ni][ks] = *(const short8*)(lds + BB8(BUF) +                      \
              (wc * 64 + ni * 16 + c) * 64 + (((ks * 4 + g) ^ cg7) << 3));     \
    }                                                                          \
    STAGE_STMT;                                                                \
    __builtin_amdgcn_sched_barrier(0);                                         \
    __builtin_amdgcn_s_barrier();                                              \
    asm volatile("s_waitcnt lgkmcnt(0)" ::: "memory");                         \
    __builtin_amdgcn_sched_barrier(0);                                         \
    __builtin_amdgcn_s_setprio(1);                                             \
    _Pragma("unroll") for (int mi2 = 0; mi2 < 2; ++mi2)                        \
      _Pragma("unroll") for (int ni = 0; ni < 4; ++ni)                         \
        _Pragma("unroll") for (int ks = 0; ks < 2; ++ks)                       \
          acc[(MIH) * 2 + mi2][ni] = __builtin_amdgcn_mfma_f32_16x16x32_bf16(  \
              afr[mi2][ks], bfr[ni][ks], acc[(MIH) * 2 + mi2][ni], 0, 0, 0);   \
    __builtin_amdgcn_s_setprio(0);                                             \
    WAIT_STMT                                                                  \
    __builtin_amdgcn_s_barrier();                                              \
  }

#define GEMM_MAIN_LOOP(A_, BT_, K_)                                            \
  STAGE(A_ + (long)m0 * K_, AB8(0, 0));                                        \
  STAGE(A_ + (long)(m0 + 128) * K_, AB8(0, 1));                                \
  STAGE(BT_ + (long)n0 * K_, BB8(0));                                          \
  STAGE(BT_ + (long)n0 * K_ + 64, BB8(1));                                     \
  VMW(2)                                                                       \
  __builtin_amdgcn_s_barrier();                                                \
  for (int it2 = 0; it2 < nt / 2 - 1; ++it2) {                                 \
    const long T1 = (long)(2 * it2 + 1) * 64;                                  \
    const long T2 = (long)(2 * it2 + 2) * 64;                                  \
    const long T3 = (long)(2 * it2 + 3) * 64;                                  \
    PHASE(0, 0, STAGE(A_ + (long)m0 * K_ + T1, AB8(1, 0)), )                   \
    PHASE(0, 1,                                                                \
          { STAGE(A_ + (long)(m0 + 128) * K_ + T1, AB8(1, 1));                 \
            STAGE(BT_ + (long)n0 * K_ + T2, BB8(0)); }, VMW(2))                \
    PHASE(1, 0, STAGE(A_ + (long)m0 * K_ + T2, AB8(0, 0)), )                   \
    PHASE(1, 1,                                                                \
          { STAGE(A_ + (long)(m0 + 128) * K_ + T2, AB8(0, 1));                 \
            STAGE(BT_ + (long)n0 * K_ + T3, BB8(1)); }, VMW(2))                \
  }                                                                            \
  {                                                                            \
    const long TL = (long)(nt - 1) * 64;                                       \
    PHASE(0, 0, STAGE(A_ + (long)m0 * K_ + TL, AB8(1, 0)), )                   \
    PHASE(0, 1, STAGE(A_ + (long)(m0 + 128) * K_ + TL, AB8(1, 1)), VMW(0))     \
    PHASE(1, 0, {}, )                                                          \
    PHASE(1, 1, {}, )                                                          \
  }

// ---------------------------------------------------------------------------
// QKV GEMM with fused rope + head-split + V-transpose epilogue (unchanged).
// ---------------------------------------------------------------------------
__global__ __launch_bounds__(512, 2) void gemm_qkv(
    const unsigned short* __restrict__ A, const unsigned short* __restrict__ BT,
    const float* __restrict__ rope, const int* __restrict__ tpos,
    unsigned short* __restrict__ qR, unsigned short* __restrict__ kR,
    unsigned short* __restrict__ vT, int K) {
  __shared__ unsigned short lds[49152];  // 96 KiB
  const int tid = threadIdx.x;
  const int wid = tid >> 6, lane = tid & 63;
  const int c = lane & 15, g = lane >> 4;
  const int wr = wid >> 1, wc = wid & 1;
  const int cg7 = c & 7;

  const int nwg = gridDim.x * gridDim.y;
  const int bid = blockIdx.y * gridDim.x + blockIdx.x;
  const int swz = (bid & 7) * (nwg >> 3) + (bid >> 3);
  const int m0 = (swz % gridDim.x) * 256, n0 = (swz / gridDim.x) * 128;

  const int nt = K >> 6;

  float4v acc[4][4];
#pragma unroll
  for (int i = 0; i < 4; ++i)
#pragma unroll
    for (int j = 0; j < 4; ++j) acc[i][j] = (float4v){0.f, 0.f, 0.f, 0.f};
  short8 bfr[4][2];

  auto STAGE = [&](const unsigned short* gbase, int sbase) {
#pragma unroll
    for (int j = 0; j < 2; ++j) {
      const int ch = j * 512 + tid;
      const int r = ch >> 3;
      const int wo = (ch & 7) ^ (r & 7);
      gload16(gbase + (long)r * K + wo * 8, lds + sbase + j * 4096 + wid * 512);
    }
  };

  GEMM_MAIN_LOOP(A, BT, K)

  const int type = n0 >> 11;            // 0=q 1=k 2=v
  const int h = (n0 & 2047) >> 7;
  const long bh = (long)((m0 >> 10) * Hn + h);
  const int s0 = m0 & 1023;

  if (type == 2) {
#pragma unroll
    for (int mi = 0; mi < 4; ++mi)
#pragma unroll
      for (int ni = 0; ni < 4; ++ni)
#pragma unroll
        for (int j = 0; j < 4; ++j) {
          const int mm = wr * 64 + mi * 16 + g * 4 + j;   // s-local
          const int nn = wc * 64 + ni * 16 + c;           // d
          lds[nn * 264 + mm] = f2bf(acc[mi][ni][j]);
        }
    __syncthreads();
    unsigned short* dst = vT + bh * (long)DHn * Sn + s0;
#pragma unroll
    for (int it = 0; it < 8; ++it) {
      const int cid = it * 512 + tid;
      const int d = cid >> 5;
      const int sl = (cid & 31) * 8;
      short8 v = *reinterpret_cast<const short8*>(lds + d * 264 + sl);
      *reinterpret_cast<short8*>(dst + (long)d * Sn + sl) = v;
    }
  } else {
#pragma unroll
    for (int mi = 0; mi < 4; ++mi)
#pragma unroll
      for (int ni = 0; ni < 4; ++ni)
#pragma unroll
        for (int j = 0; j < 4; ++j) {
          const int mm = wr * 64 + mi * 16 + g * 4 + j;
          const int nn = wc * 64 + ni * 16 + c;
          lds[mm * 136 + nn] = f2bf(acc[mi][ni][j]);
        }
    __syncthreads();
    unsigned short* dst = (type == 0 ? qR : kR) + (bh * Sn + s0) * DHn;
    const float qsc = (type == 0) ? 0.1275174213f : 1.0f;  // log2(e)/sqrt(128)
#pragma unroll
    for (int it = 0; it < 8; ++it) {
      const int cid = it * 512 + tid;
      const int r = cid >> 4;
      const int colc = (cid & 15) * 8;
      union { short8 v; unsigned short u[8]; } iw, ow;
      iw.v = *reinterpret_cast<const short8*>(lds + r * 136 + colc);
      const int pos = tpos[s0 + r];
      const float4* pe = reinterpret_cast<const float4*>(rope) +
                         (long)pos * 64 + (colc >> 1);
#pragma unroll
      for (int p = 0; p < 4; ++p) {
        const float4 m2 = pe[p];
        const float xx = bf2f(iw.u[2 * p]), yy = bf2f(iw.u[2 * p + 1]);
        ow.u[2 * p]     = f2bf((m2.x * xx + m2.y * yy) * qsc);
        ow.u[2 * p + 1] = f2bf((m2.z * xx + m2.w * yy) * qsc);
      }
      *reinterpret_cast<short8*>(dst + (long)r * DHn + colc) = ow.v;
    }
  }
}

// ---------------------------------------------------------------------------
// Out-proj GEMM (f32 out), same main loop (unchanged).
// ---------------------------------------------------------------------------
__global__ __launch_bounds__(512, 2) void gemm_out(
    const unsigned short* __restrict__ A, const unsigned short* __restrict__ BT,
    float* __restrict__ Cout, int N, int K) {
  __shared__ unsigned short lds[49152];
  const int tid = threadIdx.x;
  const int wid = tid >> 6, lane = tid & 63;
  const int c = lane & 15, g = lane >> 4;
  const int wr = wid >> 1, wc = wid & 1;
  const int cg7 = c & 7;

  const int nwg = gridDim.x * gridDim.y;
  const int bid = blockIdx.y * gridDim.x + blockIdx.x;
  const int swz = (bid & 7) * (nwg >> 3) + (bid >> 3);
  const int m0 = (swz % gridDim.x) * 256, n0 = (swz / gridDim.x) * 128;

  const int nt = K >> 6;

  float4v acc[4][4];
#pragma unroll
  for (int i = 0; i < 4; ++i)
#pragma unroll
    for (int j = 0; j < 4; ++j) acc[i][j] = (float4v){0.f, 0.f, 0.f, 0.f};
  short8 bfr[4][2];

  auto STAGE = [&](const unsigned short* gbase, int sbase) {
#pragma unroll
    for (int j = 0; j < 2; ++j) {
      const int ch = j * 512 + tid;
      const int r = ch >> 3;
      const int wo = (ch & 7) ^ (r & 7);
      gload16(gbase + (long)r * K + wo * 8, lds + sbase + j * 4096 + wid * 512);
    }
  };

  GEMM_MAIN_LOOP(A, BT, K)

#pragma unroll
  for (int mi = 0; mi < 4; ++mi)
#pragma unroll
    for (int ni = 0; ni < 4; ++ni)
#pragma unroll
      for (int j = 0; j < 4; ++j) {
        const int m = m0 + wr * 64 + mi * 16 + g * 4 + j;
        const int n = n0 + wc * 64 + ni * 16 + c;
        Cout[(long)m * N + n] = acc[mi][ni][j];
      }
}
#undef PHASE
#undef GEMM_MAIN_LOOP

// ---------------------------------------------------------------------------
// Flash attention v2: 8 waves (512 thr), QBLK=128, KVBLK=128 pair tiles.
// K dbuf 2x[128][128] + V^T dbuf 2x[128][128] (gload_lds, XOR-window swizzle)
// + Ps[8][16][72]. One barrier + one softmax fixed-cost block per 128 kv.
// Diagonal is tile-aligned: pairs per block = qt+1 exactly.
// ---------------------------------------------------------------------------
__global__ __launch_bounds__(512, 2) void attn_mfma(
    const unsigned short* __restrict__ qR, const unsigned short* __restrict__ kR,
    const unsigned short* __restrict__ vTd, unsigned short* __restrict__ ctx) {
  __shared__ unsigned short lds[65536];   // K: buf*16384; V: 32768 + buf*16384
  __shared__ unsigned short Ps[8][16][72];
  const int qt = gridDim.x - 1 - blockIdx.x;  // heavy blocks first (LPT)
  const int h = blockIdx.y, b = blockIdx.z;
  const int tid = threadIdx.x, wid = tid >> 6, lane = tid & 63;
  const int c = lane & 15, g = lane >> 4, cg7 = c & 7;
  const long bh = (long)(b * Hn + h);
  const unsigned short* kbase = kR + bh * Sn * DHn;
  const unsigned short* vbase = vTd + bh * DHn * Sn;

  short8 qf[4];
  {
    const unsigned short* qrow = qR + (bh * Sn + qt * 128 + wid * 16 + c) * DHn;
#pragma unroll
    for (int kc = 0; kc < 4; ++kc)
      qf[kc] = *reinterpret_cast<const short8*>(qrow + kc * 32 + g * 8);
  }

  // stage one PAIR (128 kv): K [128 r][16 win] + V^T [128 d][16 win]
  auto STAGE = [&](int pt, int buf) {
#pragma unroll
    for (int j = 0; j < 4; ++j) {  // K: 2048 chunks
      const int ch = j * 512 + tid;
      const int r = ch >> 4, wd = ch & 15;
      const int ws = (wd & 8) | ((wd & 7) ^ (r & 7));
      gload16(kbase + (long)pt * 16384 + r * 128 + ws * 8,
              lds + buf * 16384 + j * 4096 + wid * 512);
    }
#pragma unroll
    for (int j = 0; j < 4; ++j) {  // V^T: 2048 chunks
      const int ch = j * 512 + tid;
      const int d = ch >> 4, sw = ch & 15;
      const int ws = (sw & 8) | ((sw & 7) ^ (d & 7));
      gload16(vbase + (long)d * Sn + pt * 128 + ws * 8,
              lds + 32768 + buf * 16384 + j * 4096 + wid * 512);
    }
  };

  float m = -INFINITY, lsum = 0.f;
  float4v ot[8];
#pragma unroll
  for (int fd = 0; fd < 8; ++fd) ot[fd] = (float4v){0.f, 0.f, 0.f, 0.f};

  STAGE(0, 0);
  __syncthreads();
  int cur = 0;

  for (int pt = 0; pt <= qt; ++pt) {
    if (pt < qt) STAGE(pt + 1, cur ^ 1);  // prefetch flies under compute

    // S^T = K * Q^T over 128 kv (8 frags)
    float4v scv[8];
#pragma unroll
    for (int f = 0; f < 8; ++f) scv[f] = (float4v){0.f, 0.f, 0.f, 0.f};
    __builtin_amdgcn_s_setprio(1);
#pragma unroll
    for (int f = 0; f < 8; ++f)
#pragma unroll
      for (int kc = 0; kc < 4; ++kc) {
        const int wp = kc * 4 + g;
        const int ws = (wp & 8) | ((wp & 7) ^ cg7);
        short8 kf = *reinterpret_cast<const short8*>(
            lds + cur * 16384 + (f * 16 + c) * 128 + ws * 8);
        scv[f] = __builtin_amdgcn_mfma_f32_16x16x32_bf16(kf, qf[kc], scv[f], 0, 0, 0);
      }
    __builtin_amdgcn_s_setprio(0);

    if (pt == qt) {  // diagonal pair: mask kv_local > q_local
      const int qloc = wid * 16 + c;
#pragma unroll
      for (int f = 0; f < 8; ++f)
#pragma unroll
        for (int j = 0; j < 4; ++j)
          if (f * 16 + g * 4 + j > qloc) scv[f][j] = -INFINITY;
    }

    float tmax = -INFINITY;
#pragma unroll
    for (int f = 0; f < 8; ++f)
#pragma unroll
      for (int j = 0; j < 4; ++j) tmax = fmaxf(tmax, scv[f][j]);
    tmax = fmaxf(tmax, __shfl_xor(tmax, 16));
    tmax = fmaxf(tmax, __shfl_xor(tmax, 32));

    float mnew, corr;
    if (__all(tmax <= m + 8.f)) {         // defer-max
      mnew = m; corr = 1.f;
    } else {
      mnew = fmaxf(m, tmax);
      corr = exp2f(m - mnew);
#pragma unroll
      for (int fd = 0; fd < 8; ++fd) ot[fd] *= corr;
    }
    float psum = 0.f;
#pragma unroll
    for (int f = 0; f < 8; ++f)
#pragma unroll
      for (int j = 0; j < 4; ++j) {
        scv[f][j] = exp2f(scv[f][j] - mnew);
        psum += scv[f][j];
      }
    psum += __shfl_xor(psum, 16);
    psum += __shfl_xor(psum, 32);
    lsum = lsum * corr + psum;
    m = mnew;

    // PV per 64-kv half through Ps (WAR between halves handled by compiler
    // waitcnt on same-wave LDS ops)
#pragma unroll
    for (int h2 = 0; h2 < 2; ++h2) {
#pragma unroll
      for (int f4 = 0; f4 < 4; ++f4) {
        const int f = h2 * 4 + f4;
        unsigned int lo = (unsigned)f2bf(scv[f][0]) | ((unsigned)f2bf(scv[f][1]) << 16);
        unsigned int hi = (unsigned)f2bf(scv[f][2]) | ((unsigned)f2bf(scv[f][3]) << 16);
        uint2 pk; pk.x = lo; pk.y = hi;
        *reinterpret_cast<uint2*>(&Ps[wid][c][f4 * 16 + g * 4]) = pk;
      }
      short8 pf0 = *reinterpret_cast<const short8*>(&Ps[wid][c][g * 8]);
      short8 pf1 = *reinterpret_cast<const short8*>(&Ps[wid][c][32 + g * 8]);
      __builtin_amdgcn_s_setprio(1);
#pragma unroll
      for (int fd = 0; fd < 8; ++fd) {
        const int w0 = h2 * 8 + g;        // kss=0 window
        const int w1 = h2 * 8 + 4 + g;    // kss=1 window
        short8 vf0 = *reinterpret_cast<const short8*>(
            lds + 32768 + cur * 16384 + (fd * 16 + c) * 128 +
            (((w0 & 8) | ((w0 & 7) ^ cg7)) << 3));
        short8 vf1 = *reinterpret_cast<const short8*>(
            lds + 32768 + cur * 16384 + (fd * 16 + c) * 128 +
            (((w1 & 8) | ((w1 & 7) ^ cg7)) << 3));
        ot[fd] = __builtin_amdgcn_mfma_f32_16x16x32_bf16(vf0, pf0, ot[fd], 0, 0, 0);
        ot[fd] = __builtin_amdgcn_mfma_f32_16x16x32_bf16(vf1, pf1, ot[fd], 0, 0, 0);
      }
      __builtin_amdgcn_s_setprio(0);
    }

    __syncthreads();  // drains this pair's prefetch + barrier
    cur ^= 1;
  }

  const float inv = 1.0f / lsum;
  unsigned short* orow = ctx + (long)(b * Sn + qt * 128 + wid * 16 + c) * Dn + h * DHn;
#pragma unroll
  for (int fd = 0; fd < 8; ++fd) {
    const int d = fd * 16 + g * 4;
    uint2 pk;
    pk.x = (unsigned)f2bf(ot[fd][0] * inv) | ((unsigned)f2bf(ot[fd][1] * inv) << 16);
    pk.y = (unsigned)f2bf(ot[fd][2] * inv) | ((unsigned)f2bf(ot[fd][3] * inv) << 16);
    *reinterpret_cast<uint2*>(orow + d) = pk;
  }
}

// ---------------------------------------------------------------------------
extern "C" void kernel_launch(void* const* d_in, const int* in_sizes, int n_in,
                              void* d_out, int out_size, void* d_ws, size_t ws_size,
                              hipStream_t stream) {
  const float* x     = (const float*)d_in[0];
  const float* w_qkv = (const float*)d_in[1];
  const float* w_out = (const float*)d_in[2];
  const float* rope  = (const float*)d_in[3];
  const int*   tpos  = (const int*)d_in[4];
  float* out = (float*)d_out;

  unsigned short* x16    = (unsigned short*)d_ws;
  unsigned short* wqkvT  = x16 + (size_t)BS * Dn;
  unsigned short* woutT  = wqkvT + (size_t)Dn * QKVC;
  unsigned short* qR     = woutT + (size_t)Dn * Dn;
  unsigned short* kR     = qR + (size_t)BS * Dn;
  unsigned short* vT16   = kR + (size_t)BS * Dn;
  unsigned short* ctx16  = vT16 + (size_t)BS * Dn;

  cvt_f32_bf16<<<(BS * Dn / 8 + 255) / 256, 256, 0, stream>>>(x, x16, BS * Dn / 8);
  {
    dim3 g1(QKVC / 64, Dn / 64);
    transpose_cvt<<<g1, 256, 0, stream>>>(w_qkv, wqkvT, Dn, QKVC);
    dim3 g2(Dn / 64, Dn / 64);
    transpose_cvt<<<g2, 256, 0, stream>>>(w_out, woutT, Dn, Dn);
  }
  {
    dim3 grid(BS / 256, QKVC / 128);  // 16 x 48 = 768
    gemm_qkv<<<grid, 512, 0, stream>>>(x16, wqkvT, rope, tpos, qR, kR, vT16, Dn);
  }
  {
    dim3 grid(Sn / 128, Hn, Bn);      // 8 x 16 x 4 = 512
    attn_mfma<<<grid, 512, 0, stream>>>(qR, kR, vT16, ctx16);
  }
  {
    dim3 grid(BS / 256, Dn / 128);    // 16 x 16 = 256
    gemm_out<<<grid, 512, 0, stream>>>(ctx16, woutT, out, Dn, Dn);
  }
}

// Round 10
// 255.200 us; speedup vs baseline: 1.0331x; 1.0331x over previous
//
#include <hip/hip_runtime.h>
#include <hip/hip_bf16.h>
#include <math.h>

#define Bn 4
#define Sn 1024
#define Dn 2048
#define Hn 16
#define DHn 128
#define BS (Bn * Sn)       // 4096
#define QKVC (3 * Dn)      // 6144

typedef __attribute__((ext_vector_type(8))) short short8;   // 8 x bf16
typedef __attribute__((ext_vector_type(4))) float float4v;  // MFMA acc

// f32 -> bf16 (round-to-nearest-even)
__device__ inline unsigned short f2bf(float x) {
  union { float f; unsigned int u; } v; v.f = x;
  unsigned int r = v.u + 0x7fffu + ((v.u >> 16) & 1u);
  return (unsigned short)(r >> 16);
}
__device__ inline float bf2f(unsigned short b) {
  union { unsigned int u; float f; } v; v.u = ((unsigned int)b) << 16;
  return v.f;
}

// async global->LDS, 16B per lane. LDS dest = wave-uniform base + lane*16.
__device__ __forceinline__ void gload16(const unsigned short* g, unsigned short* l) {
  __builtin_amdgcn_global_load_lds(
      (const __attribute__((address_space(1))) unsigned int*)g,
      (__attribute__((address_space(3))) unsigned int*)l, 16, 0, 0);
}

// ---------------------------------------------------------------------------
// x f32 -> bf16, 8 elems/thread
// ---------------------------------------------------------------------------
__global__ __launch_bounds__(256) void cvt_f32_bf16(
    const float* __restrict__ in, unsigned short* __restrict__ out, int n8) {
  int id = blockIdx.x * 256 + threadIdx.x;
  if (id >= n8) return;
  const float4* p = reinterpret_cast<const float4*>(in) + 2 * (size_t)id;
  float4 a = p[0], b = p[1];
  short8 o;
  o[0] = (short)f2bf(a.x); o[1] = (short)f2bf(a.y);
  o[2] = (short)f2bf(a.z); o[3] = (short)f2bf(a.w);
  o[4] = (short)f2bf(b.x); o[5] = (short)f2bf(b.y);
  o[6] = (short)f2bf(b.z); o[7] = (short)f2bf(b.w);
  *reinterpret_cast<short8*>(out + 8 * (size_t)id) = o;
}

// ---------------------------------------------------------------------------
// Weight transpose+convert: w [K][N] f32 -> wT [N][K] bf16. 64x64 tiles.
// ---------------------------------------------------------------------------
__global__ __launch_bounds__(256) void transpose_cvt(
    const float* __restrict__ w, unsigned short* __restrict__ wT, int K, int N) {
  __shared__ unsigned short t[64][72];
  const int c0 = blockIdx.x * 64;  // N
  const int r0 = blockIdx.y * 64;  // K
  const int tid = threadIdx.x;
  const int r = tid >> 2;
  const int cb = (tid & 3) * 16;
#pragma unroll
  for (int it = 0; it < 4; ++it) {
    float4 v = *reinterpret_cast<const float4*>(&w[(long)(r0 + r) * N + c0 + cb + 4 * it]);
    t[r][cb + 4 * it + 0] = f2bf(v.x);
    t[r][cb + 4 * it + 1] = f2bf(v.y);
    t[r][cb + 4 * it + 2] = f2bf(v.z);
    t[r][cb + 4 * it + 3] = f2bf(v.w);
  }
  __syncthreads();
  unsigned short o[16];
#pragma unroll
  for (int e = 0; e < 16; ++e) o[e] = t[cb + e][r];
  unsigned short* dst = &wT[(long)(c0 + r) * K + r0 + cb];
  *reinterpret_cast<short8*>(dst) = *reinterpret_cast<short8*>(&o[0]);
  *reinterpret_cast<short8*>(dst + 8) = *reinterpret_cast<short8*>(&o[8]);
}

// ---------------------------------------------------------------------------
// Shared 256x128-tile pipelined main loop (unchanged from R8).
// ---------------------------------------------------------------------------
#define AB8(buf, h) ((buf) * 16384 + (h) * 8192)      // shorts
#define BB8(buf) (32768 + (buf) * 8192)               // shorts

#define VMW(n)                                                                 \
  asm volatile("s_waitcnt vmcnt(" #n ")" ::: "memory");                        \
  __builtin_amdgcn_sched_barrier(0);

#define PHASE(BUF, MIH, STAGE_STMT, WAIT_STMT)                                 \
  {                                                                            \
    __builtin_amdgcn_sched_barrier(0);                                         \
    short8 afr[2][2];                                                          \
    _Pragma("unroll") for (int mi2 = 0; mi2 < 2; ++mi2) {                      \
      const int mrow = wr * 64 + ((MIH) * 2 + mi2) * 16;                       \
      const int hh = mrow >> 7;                                                \
      const int rl = (mrow & 127) + c;                                         \
      _Pragma("unroll") for (int ks = 0; ks < 2; ++ks)                         \
        afr[mi2][ks] = *(const short8*)(lds + AB8(BUF, 0) + hh * 8192 +        \
            rl * 64 + (((ks * 4 + g) ^ cg7) << 3));                            \
    }                                                                          \
    if ((MIH) == 0) {                                                          \
      _Pragma("unroll") for (int ni = 0; ni < 4; ++ni)                         \
        _Pragma("unroll") for (int ks = 0; ks < 2; ++ks)                       \
          bfr[ni][ks] = *(const short8*)(lds + BB8(BUF) +                      \
              (wc * 64 + ni * 16 + c) * 64 + (((ks * 4 + g) ^ cg7) << 3));     \
    }                                                                          \
    STAGE_STMT;                                                                \
    __builtin_amdgcn_sched_barrier(0);                                         \
    __builtin_amdgcn_s_barrier();                                              \
    asm volatile("s_waitcnt lgkmcnt(0)" ::: "memory");                         \
    __builtin_amdgcn_sched_barrier(0);                                         \
    __builtin_amdgcn_s_setprio(1);                                             \
    _Pragma("unroll") for (int mi2 = 0; mi2 < 2; ++mi2)                        \
      _Pragma("unroll") for (int ni = 0; ni < 4; ++ni)                         \
        _Pragma("unroll") for (int ks = 0; ks < 2; ++ks)                       \
          acc[(MIH) * 2 + mi2][ni] = __builtin_amdgcn_mfma_f32_16x16x32_bf16(  \
              afr[mi2][ks], bfr[ni][ks], acc[(MIH) * 2 + mi2][ni], 0, 0, 0);   \
    __builtin_amdgcn_s_setprio(0);                                             \
    WAIT_STMT                                                                  \
    __builtin_amdgcn_s_barrier();                                              \
  }

#define GEMM_MAIN_LOOP(A_, BT_, K_)                                            \
  STAGE(A_ + (long)m0 * K_, AB8(0, 0));                                        \
  STAGE(A_ + (long)(m0 + 128) * K_, AB8(0, 1));                                \
  STAGE(BT_ + (long)n0 * K_, BB8(0));                                          \
  STAGE(BT_ + (long)n0 * K_ + 64, BB8(1));                                     \
  VMW(2)                                                                       \
  __builtin_amdgcn_s_barrier();                                                \
  for (int it2 = 0; it2 < nt / 2 - 1; ++it2) {                                 \
    const long T1 = (long)(2 * it2 + 1) * 64;                                  \
    const long T2 = (long)(2 * it2 + 2) * 64;                                  \
    const long T3 = (long)(2 * it2 + 3) * 64;                                  \
    PHASE(0, 0, STAGE(A_ + (long)m0 * K_ + T1, AB8(1, 0)), )                   \
    PHASE(0, 1,                                                                \
          { STAGE(A_ + (long)(m0 + 128) * K_ + T1, AB8(1, 1));                 \
            STAGE(BT_ + (long)n0 * K_ + T2, BB8(0)); }, VMW(2))                \
    PHASE(1, 0, STAGE(A_ + (long)m0 * K_ + T2, AB8(0, 0)), )                   \
    PHASE(1, 1,                                                                \
          { STAGE(A_ + (long)(m0 + 128) * K_ + T2, AB8(0, 1));                 \
            STAGE(BT_ + (long)n0 * K_ + T3, BB8(1)); }, VMW(2))                \
  }                                                                            \
  {                                                                            \
    const long TL = (long)(nt - 1) * 64;                                       \
    PHASE(0, 0, STAGE(A_ + (long)m0 * K_ + TL, AB8(1, 0)), )                   \
    PHASE(0, 1, STAGE(A_ + (long)(m0 + 128) * K_ + TL, AB8(1, 1)), VMW(0))     \
    PHASE(1, 0, {}, )                                                          \
    PHASE(1, 1, {}, )                                                          \
  }

// ---------------------------------------------------------------------------
// QKV GEMM with fused rope + head-split + V-transpose epilogue (unchanged).
// ---------------------------------------------------------------------------
__global__ __launch_bounds__(512, 2) void gemm_qkv(
    const unsigned short* __restrict__ A, const unsigned short* __restrict__ BT,
    const float* __restrict__ rope, const int* __restrict__ tpos,
    unsigned short* __restrict__ qR, unsigned short* __restrict__ kR,
    unsigned short* __restrict__ vT, int K) {
  __shared__ unsigned short lds[49152];  // 96 KiB
  const int tid = threadIdx.x;
  const int wid = tid >> 6, lane = tid & 63;
  const int c = lane & 15, g = lane >> 4;
  const int wr = wid >> 1, wc = wid & 1;
  const int cg7 = c & 7;

  const int nwg = gridDim.x * gridDim.y;
  const int bid = blockIdx.y * gridDim.x + blockIdx.x;
  const int swz = (bid & 7) * (nwg >> 3) + (bid >> 3);
  const int m0 = (swz % gridDim.x) * 256, n0 = (swz / gridDim.x) * 128;

  const int nt = K >> 6;

  float4v acc[4][4];
#pragma unroll
  for (int i = 0; i < 4; ++i)
#pragma unroll
    for (int j = 0; j < 4; ++j) acc[i][j] = (float4v){0.f, 0.f, 0.f, 0.f};
  short8 bfr[4][2];

  auto STAGE = [&](const unsigned short* gbase, int sbase) {
#pragma unroll
    for (int j = 0; j < 2; ++j) {
      const int ch = j * 512 + tid;
      const int r = ch >> 3;
      const int wo = (ch & 7) ^ (r & 7);
      gload16(gbase + (long)r * K + wo * 8, lds + sbase + j * 4096 + wid * 512);
    }
  };

  GEMM_MAIN_LOOP(A, BT, K)

  const int type = n0 >> 11;            // 0=q 1=k 2=v
  const int h = (n0 & 2047) >> 7;
  const long bh = (long)((m0 >> 10) * Hn + h);
  const int s0 = m0 & 1023;

  if (type == 2) {
#pragma unroll
    for (int mi = 0; mi < 4; ++mi)
#pragma unroll
      for (int ni = 0; ni < 4; ++ni)
#pragma unroll
        for (int j = 0; j < 4; ++j) {
          const int mm = wr * 64 + mi * 16 + g * 4 + j;   // s-local
          const int nn = wc * 64 + ni * 16 + c;           // d
          lds[nn * 264 + mm] = f2bf(acc[mi][ni][j]);
        }
    __syncthreads();
    unsigned short* dst = vT + bh * (long)DHn * Sn + s0;
#pragma unroll
    for (int it = 0; it < 8; ++it) {
      const int cid = it * 512 + tid;
      const int d = cid >> 5;
      const int sl = (cid & 31) * 8;
      short8 v = *reinterpret_cast<const short8*>(lds + d * 264 + sl);
      *reinterpret_cast<short8*>(dst + (long)d * Sn + sl) = v;
    }
  } else {
#pragma unroll
    for (int mi = 0; mi < 4; ++mi)
#pragma unroll
      for (int ni = 0; ni < 4; ++ni)
#pragma unroll
        for (int j = 0; j < 4; ++j) {
          const int mm = wr * 64 + mi * 16 + g * 4 + j;
          const int nn = wc * 64 + ni * 16 + c;
          lds[mm * 136 + nn] = f2bf(acc[mi][ni][j]);
        }
    __syncthreads();
    unsigned short* dst = (type == 0 ? qR : kR) + (bh * Sn + s0) * DHn;
    const float qsc = (type == 0) ? 0.1275174213f : 1.0f;  // log2(e)/sqrt(128)
#pragma unroll
    for (int it = 0; it < 8; ++it) {
      const int cid = it * 512 + tid;
      const int r = cid >> 4;
      const int colc = (cid & 15) * 8;
      union { short8 v; unsigned short u[8]; } iw, ow;
      iw.v = *reinterpret_cast<const short8*>(lds + r * 136 + colc);
      const int pos = tpos[s0 + r];
      const float4* pe = reinterpret_cast<const float4*>(rope) +
                         (long)pos * 64 + (colc >> 1);
#pragma unroll
      for (int p = 0; p < 4; ++p) {
        const float4 m2 = pe[p];
        const float xx = bf2f(iw.u[2 * p]), yy = bf2f(iw.u[2 * p + 1]);
        ow.u[2 * p]     = f2bf((m2.x * xx + m2.y * yy) * qsc);
        ow.u[2 * p + 1] = f2bf((m2.z * xx + m2.w * yy) * qsc);
      }
      *reinterpret_cast<short8*>(dst + (long)r * DHn + colc) = ow.v;
    }
  }
}

// ---------------------------------------------------------------------------
// Out-proj GEMM (f32 out), same main loop (unchanged).
// ---------------------------------------------------------------------------
__global__ __launch_bounds__(512, 2) void gemm_out(
    const unsigned short* __restrict__ A, const unsigned short* __restrict__ BT,
    float* __restrict__ Cout, int N, int K) {
  __shared__ unsigned short lds[49152];
  const int tid = threadIdx.x;
  const int wid = tid >> 6, lane = tid & 63;
  const int c = lane & 15, g = lane >> 4;
  const int wr = wid >> 1, wc = wid & 1;
  const int cg7 = c & 7;

  const int nwg = gridDim.x * gridDim.y;
  const int bid = blockIdx.y * gridDim.x + blockIdx.x;
  const int swz = (bid & 7) * (nwg >> 3) + (bid >> 3);
  const int m0 = (swz % gridDim.x) * 256, n0 = (swz / gridDim.x) * 128;

  const int nt = K >> 6;

  float4v acc[4][4];
#pragma unroll
  for (int i = 0; i < 4; ++i)
#pragma unroll
    for (int j = 0; j < 4; ++j) acc[i][j] = (float4v){0.f, 0.f, 0.f, 0.f};
  short8 bfr[4][2];

  auto STAGE = [&](const unsigned short* gbase, int sbase) {
#pragma unroll
    for (int j = 0; j < 2; ++j) {
      const int ch = j * 512 + tid;
      const int r = ch >> 3;
      const int wo = (ch & 7) ^ (r & 7);
      gload16(gbase + (long)r * K + wo * 8, lds + sbase + j * 4096 + wid * 512);
    }
  };

  GEMM_MAIN_LOOP(A, BT, K)

#pragma unroll
  for (int mi = 0; mi < 4; ++mi)
#pragma unroll
    for (int ni = 0; ni < 4; ++ni)
#pragma unroll
      for (int j = 0; j < 4; ++j) {
        const int m = m0 + wr * 64 + mi * 16 + g * 4 + j;
        const int n = n0 + wc * 64 + ni * 16 + c;
        Cout[(long)m * N + n] = acc[mi][ni][j];
      }
}
#undef PHASE
#undef GEMM_MAIN_LOOP

// ---------------------------------------------------------------------------
// Flash attention v3: 4 waves (256 thr), KVBLK=64 double-buffered (v1 shell,
// 41 KB LDS -> 2 blocks/CU), but QBLK=128 via TWO 64-row q-subtiles sharing
// every staged K/V tile: stage+barrier cost per q-row halved, MFMA unchanged.
// ---------------------------------------------------------------------------
__global__ __launch_bounds__(256, 2) void attn_mfma(
    const unsigned short* __restrict__ qR, const unsigned short* __restrict__ kR,
    const unsigned short* __restrict__ vTd, unsigned short* __restrict__ ctx) {
  __shared__ unsigned short lds[32768];   // K dbuf @0/8192, V dbuf @16384/24576
  __shared__ unsigned short Ps[4][16][72];
  const int qp = gridDim.x - 1 - blockIdx.x;  // heavy blocks first (LPT)
  const int h = blockIdx.y, b = blockIdx.z;
  const int tid = threadIdx.x, wid = tid >> 6, lane = tid & 63;
  const int c = lane & 15, g = lane >> 4, cg7 = c & 7;
  const long bh = (long)(b * Hn + h);
  const unsigned short* kbase = kR + bh * Sn * DHn;
  const unsigned short* vbase = vTd + bh * DHn * Sn;

  // Q fragments for both 64-row subtiles
  short8 qf[2][4];
#pragma unroll
  for (int sub = 0; sub < 2; ++sub) {
    const unsigned short* qrow =
        qR + (bh * Sn + qp * 128 + sub * 64 + wid * 16 + c) * DHn;
#pragma unroll
    for (int kc = 0; kc < 4; ++kc)
      qf[sub][kc] = *reinterpret_cast<const short8*>(qrow + kc * 32 + g * 8);
  }

  auto STAGE = [&](int kt, int buf) {
#pragma unroll
    for (int j = 0; j < 4; ++j) {  // K tile [64][128]
      const int ch = j * 256 + tid;
      const int r = ch >> 4, wd = ch & 15;
      const int ws = (wd & 8) | ((wd & 7) ^ (r & 7));
      gload16(kbase + (long)kt * 8192 + r * 128 + ws * 8,
              lds + buf * 8192 + j * 2048 + wid * 512);
    }
#pragma unroll
    for (int j = 0; j < 4; ++j) {  // V^T tile [128][64]
      const int ch = j * 256 + tid;
      const int d = ch >> 3, sw = ch & 7;
      gload16(vbase + (long)d * Sn + kt * 64 + ((sw ^ (d & 7)) << 3),
              lds + 16384 + buf * 8192 + j * 2048 + wid * 512);
    }
  };

  float m[2] = {-INFINITY, -INFINITY}, lsum[2] = {0.f, 0.f};
  float4v otA[8], otB[8];
#pragma unroll
  for (int fd = 0; fd < 8; ++fd) {
    otA[fd] = (float4v){0.f, 0.f, 0.f, 0.f};
    otB[fd] = (float4v){0.f, 0.f, 0.f, 0.f};
  }

  const int ntt = 2 * qp + 2;  // kv tiles needed by qsub1
  STAGE(0, 0);
  __syncthreads();
  int cur = 0;

  for (int kt = 0; kt < ntt; ++kt) {
    if (kt + 1 < ntt) STAGE(kt + 1, cur ^ 1);  // prefetch flies under compute

#pragma unroll
    for (int sub = 0; sub < 2; ++sub) {
      if (sub == 0 && kt == ntt - 1) continue;  // qsub0 doesn't need last tile
      float4v* ot = (sub == 0) ? otA : otB;

      // S^T = K * Q^T
      float4v scv[4];
#pragma unroll
      for (int f = 0; f < 4; ++f) scv[f] = (float4v){0.f, 0.f, 0.f, 0.f};
      __builtin_amdgcn_s_setprio(1);
#pragma unroll
      for (int f = 0; f < 4; ++f)
#pragma unroll
        for (int kc = 0; kc < 4; ++kc) {
          const int wp = kc * 4 + g;
          const int ws = (wp & 8) | ((wp & 7) ^ cg7);
          short8 kf = *reinterpret_cast<const short8*>(
              lds + cur * 8192 + (f * 16 + c) * 128 + ws * 8);
          scv[f] = __builtin_amdgcn_mfma_f32_16x16x32_bf16(kf, qf[sub][kc],
                                                           scv[f], 0, 0, 0);
        }
      __builtin_amdgcn_s_setprio(0);

      if (kt == 2 * qp + sub) {  // this subtile's diagonal
        const int qloc = wid * 16 + c;
#pragma unroll
        for (int f = 0; f < 4; ++f)
#pragma unroll
          for (int j = 0; j < 4; ++j)
            if (f * 16 + g * 4 + j > qloc) scv[f][j] = -INFINITY;
      }

      float tmax = -INFINITY;
#pragma unroll
      for (int f = 0; f < 4; ++f)
#pragma unroll
        for (int j = 0; j < 4; ++j) tmax = fmaxf(tmax, scv[f][j]);
      tmax = fmaxf(tmax, __shfl_xor(tmax, 16));
      tmax = fmaxf(tmax, __shfl_xor(tmax, 32));

      float mnew, corr;
      if (__all(tmax <= m[sub] + 8.f)) {  // defer-max
        mnew = m[sub]; corr = 1.f;
      } else {
        mnew = fmaxf(m[sub], tmax);
        corr = exp2f(m[sub] - mnew);
#pragma unroll
        for (int fd = 0; fd < 8; ++fd) ot[fd] *= corr;
      }
      float psum = 0.f;
#pragma unroll
      for (int f = 0; f < 4; ++f)
#pragma unroll
        for (int j = 0; j < 4; ++j) {
          scv[f][j] = exp2f(scv[f][j] - mnew);
          psum += scv[f][j];
        }
      psum += __shfl_xor(psum, 16);
      psum += __shfl_xor(psum, 32);
      lsum[sub] = lsum[sub] * corr + psum;
      m[sub] = mnew;

#pragma unroll
      for (int f = 0; f < 4; ++f) {
        unsigned int lo = (unsigned)f2bf(scv[f][0]) | ((unsigned)f2bf(scv[f][1]) << 16);
        unsigned int hi = (unsigned)f2bf(scv[f][2]) | ((unsigned)f2bf(scv[f][3]) << 16);
        uint2 pk; pk.x = lo; pk.y = hi;
        *reinterpret_cast<uint2*>(&Ps[wid][c][f * 16 + g * 4]) = pk;
      }

      short8 pf0 = *reinterpret_cast<const short8*>(&Ps[wid][c][g * 8]);
      short8 pf1 = *reinterpret_cast<const short8*>(&Ps[wid][c][32 + g * 8]);
      __builtin_amdgcn_s_setprio(1);
#pragma unroll
      for (int fd = 0; fd < 8; ++fd) {
        short8 vf0 = *reinterpret_cast<const short8*>(
            lds + 16384 + cur * 8192 + (fd * 16 + c) * 64 + ((g ^ cg7) << 3));
        short8 vf1 = *reinterpret_cast<const short8*>(
            lds + 16384 + cur * 8192 + (fd * 16 + c) * 64 + (((g + 4) ^ cg7) << 3));
        ot[fd] = __builtin_amdgcn_mfma_f32_16x16x32_bf16(vf0, pf0, ot[fd], 0, 0, 0);
        ot[fd] = __builtin_amdgcn_mfma_f32_16x16x32_bf16(vf1, pf1, ot[fd], 0, 0, 0);
      }
      __builtin_amdgcn_s_setprio(0);
    }

    __syncthreads();  // drains this tile's prefetch + barrier
    cur ^= 1;
  }

  // epilogue: both subtiles
#pragma unroll
  for (int sub = 0; sub < 2; ++sub) {
    const float4v* ot = (sub == 0) ? otA : otB;
    const float inv = 1.0f / lsum[sub];
    unsigned short* orow =
        ctx + (long)(b * Sn + qp * 128 + sub * 64 + wid * 16 + c) * Dn + h * DHn;
#pragma unroll
    for (int fd = 0; fd < 8; ++fd) {
      const int d = fd * 16 + g * 4;
      uint2 pk;
      pk.x = (unsigned)f2bf(ot[fd][0] * inv) | ((unsigned)f2bf(ot[fd][1] * inv) << 16);
      pk.y = (unsigned)f2bf(ot[fd][2] * inv) | ((unsigned)f2bf(ot[fd][3] * inv) << 16);
      *reinterpret_cast<uint2*>(orow + d) = pk;
    }
  }
}

// ---------------------------------------------------------------------------
extern "C" void kernel_launch(void* const* d_in, const int* in_sizes, int n_in,
                              void* d_out, int out_size, void* d_ws, size_t ws_size,
                              hipStream_t stream) {
  const float* x     = (const float*)d_in[0];
  const float* w_qkv = (const float*)d_in[1];
  const float* w_out = (const float*)d_in[2];
  const float* rope  = (const float*)d_in[3];
  const int*   tpos  = (const int*)d_in[4];
  float* out = (float*)d_out;

  unsigned short* x16    = (unsigned short*)d_ws;
  unsigned short* wqkvT  = x16 + (size_t)BS * Dn;
  unsigned short* woutT  = wqkvT + (size_t)Dn * QKVC;
  unsigned short* qR     = woutT + (size_t)Dn * Dn;
  unsigned short* kR     = qR + (size_t)BS * Dn;
  unsigned short* vT16   = kR + (size_t)BS * Dn;
  unsigned short* ctx16  = vT16 + (size_t)BS * Dn;

  cvt_f32_bf16<<<(BS * Dn / 8 + 255) / 256, 256, 0, stream>>>(x, x16, BS * Dn / 8);
  {
    dim3 g1(QKVC / 64, Dn / 64);
    transpose_cvt<<<g1, 256, 0, stream>>>(w_qkv, wqkvT, Dn, QKVC);
    dim3 g2(Dn / 64, Dn / 64);
    transpose_cvt<<<g2, 256, 0, stream>>>(w_out, woutT, Dn, Dn);
  }
  {
    dim3 grid(BS / 256, QKVC / 128);  // 16 x 48 = 768
    gemm_qkv<<<grid, 512, 0, stream>>>(x16, wqkvT, rope, tpos, qR, kR, vT16, Dn);
  }
  {
    dim3 grid(Sn / 128, Hn, Bn);      // 8 x 16 x 4 = 512
    attn_mfma<<<grid, 256, 0, stream>>>(qR, kR, vT16, ctx16);
  }
  {
    dim3 grid(BS / 256, Dn / 128);    // 16 x 16 = 256
    gemm_out<<<grid, 512, 0, stream>>>(ctx16, woutT, out, Dn, Dn);
  }
}